// Round 6
// baseline (113.004 us; speedup 1.0000x reference)
//
#include <hip/hip_runtime.h>
#include <hip/hip_bf16.h>

// LRGCN_Batch — reference returns ONLY h2, so the _relation() path is dead.
// Live math, REASSOCIATED ((A·x)@W == A·(x@W), A = weighted-mean gather op):
//   Y1 = x @ W1            (bf16 MFMA, fp32 acc, bf16 store, SLICED layout)
//   h1 = elu(gather_mean(Y1, adj1_w2))   (fp32 acc, bf16 store)
//   Y2 = h1 @ W2           (bf16 MFMA, fp32 acc, bf16 store, SLICED layout)
//   out = gather_mean(Y2, adj2_w2)       (fp32 out)
// R6: XCD-sliced gather. Y1 stored as 8 slices of 16 cols ([8][N][16] bf16,
// 1.6MB/slice), Y2 as 8 slices of 8 cols (0.8MB/slice). Gather blocks use
// slice = bid%8 -> with round-robin block->XCD dispatch, each XCD's 4MB L2
// holds only its slice -> gather reads become L2 hits (R3 evidence: misses
// were served at only ~3 TB/s and dominated). Load granule kept at 16B/lane
// (2 lanes/node @32B rows, 1 lane/node @16B rows) so VMEM request count does
// not increase. idx/w staged with nontemporal loads (streaming; don't evict
// the slice). Arithmetic identical to R5 -> absmax 2.44e-4 unchanged.

#define NN   50000
#define KNBR 16
#define NF   128   // NFEAT == NHID
#define NC   64    // NCLASS

typedef short s16x8 __attribute__((ext_vector_type(8)));  // 8 bf16 (4 VGPR)
typedef float f32x4 __attribute__((ext_vector_type(4)));

static __device__ __forceinline__ unsigned short f2bf(float f) {
  __hip_bfloat16 h = __float2bfloat16(f);  // RNE
  return reinterpret_cast<unsigned short&>(h);
}
static __device__ __forceinline__ float bflo(unsigned int u) {
  return __uint_as_float(u << 16);
}
static __device__ __forceinline__ float bfhi(unsigned int u) {
  return __uint_as_float(u & 0xffff0000u);
}

// ---------------- MFMA GEMM: C_bf16 = A[M x 128] @ B_f32[128 x BN_] --------
// Same compute as R5 (m89-verified fragment layouts); epilogue stores into
// the SLICED layout: BN=128 -> [8][NN][16] (slice=col/16), BN=64 ->
// [8][NN][8] (slice=col/8).
template <int BN_, bool ABF16>
__global__ __launch_bounds__(256, 2) void gemm_mfma(
    const void* __restrict__ Ap, const float* __restrict__ B,
    unsigned short* __restrict__ C, int M) {
  constexpr int CT = BN_ / 16;  // col tiles: 8 or 4
  constexpr int KP = 136;       // LDS row stride in bf16 (272B: 16B-aligned)
  __shared__ unsigned short Wt_s[BN_ * KP];
  __shared__ unsigned short st_s[4][16 * KP];

  const int t = threadIdx.x;
  for (int i = t; i < 128 * BN_; i += 256) {   // stage W^T as bf16
    const int k = i / BN_, c = i % BN_;
    Wt_s[c * KP + k] = f2bf(B[i]);
  }
  __syncthreads();

  const int w   = t >> 6;
  const int l   = t & 63;
  const int lr  = l & 15;   // row-in-mtile (A) / col-in-ctile (B,D)
  const int lk  = l >> 4;   // k-quarter / D row-quad
  const int bm0 = blockIdx.x * 128 + w * 32;

  const int row0 = bm0 + lr, row1 = row0 + 16;
  const int r0c = row0 < M ? row0 : M - 1;  // clamp loads (dup row, safe)
  const int r1c = row1 < M ? row1 : M - 1;

  f32x4 acc[2][CT];
#pragma unroll
  for (int mt = 0; mt < 2; ++mt)
#pragma unroll
    for (int ct = 0; ct < CT; ++ct) acc[mt][ct] = (f32x4){0.f, 0.f, 0.f, 0.f};

#pragma unroll
  for (int ks = 0; ks < 4; ++ks) {
    s16x8 af[2];
    if (ABF16) {
      const uint4* A4 = reinterpret_cast<const uint4*>(Ap);
      af[0] = __builtin_bit_cast(s16x8, A4[(size_t)r0c * (NF / 8) + ks * 4 + lk]);
      af[1] = __builtin_bit_cast(s16x8, A4[(size_t)r1c * (NF / 8) + ks * 4 + lk]);
    } else {
      const float4* A4 = reinterpret_cast<const float4*>(Ap);
      const float4 u0 = A4[(size_t)r0c * 32 + ks * 8 + lk * 2];
      const float4 u1 = A4[(size_t)r0c * 32 + ks * 8 + lk * 2 + 1];
      const float4 v0 = A4[(size_t)r1c * 32 + ks * 8 + lk * 2];
      const float4 v1 = A4[(size_t)r1c * 32 + ks * 8 + lk * 2 + 1];
      unsigned short a0[8] = {f2bf(u0.x), f2bf(u0.y), f2bf(u0.z), f2bf(u0.w),
                              f2bf(u1.x), f2bf(u1.y), f2bf(u1.z), f2bf(u1.w)};
      unsigned short a1[8] = {f2bf(v0.x), f2bf(v0.y), f2bf(v0.z), f2bf(v0.w),
                              f2bf(v1.x), f2bf(v1.y), f2bf(v1.z), f2bf(v1.w)};
      af[0] = __builtin_bit_cast(s16x8, *(uint4*)a0);
      af[1] = __builtin_bit_cast(s16x8, *(uint4*)a1);
    }
    const int kb = ks * 32 + lk * 8;
#pragma unroll
    for (int ct = 0; ct < CT; ++ct) {
      const uint4 bw = *reinterpret_cast<const uint4*>(&Wt_s[(ct * 16 + lr) * KP + kb]);
      const s16x8 bf = __builtin_bit_cast(s16x8, bw);
      acc[0][ct] = __builtin_amdgcn_mfma_f32_16x16x32_bf16(af[0], bf, acc[0][ct], 0, 0, 0);
      acc[1][ct] = __builtin_amdgcn_mfma_f32_16x16x32_bf16(af[1], bf, acc[1][ct], 0, 0, 0);
    }
  }

  unsigned short* st = st_s[w];
  uint4* C4 = reinterpret_cast<uint4*>(C);
#pragma unroll
  for (int mt = 0; mt < 2; ++mt) {
#pragma unroll
    for (int ct = 0; ct < CT; ++ct)
#pragma unroll
      for (int r = 0; r < 4; ++r)
        st[(lk * 4 + r) * KP + ct * 16 + lr] = f2bf(acc[mt][ct][r]);
    // wave-internal LDS readback (same wave wrote it; compiler waits lgkmcnt)
    if (BN_ == 128) {
#pragma unroll
      for (int p = 0; p < 4; ++p) {
        const int ri = p * 4 + lk;
        const int grow = bm0 + mt * 16 + ri;
        if (grow < M) {
          const uint4 v = *reinterpret_cast<const uint4*>(&st[ri * KP + lr * 8]);
          // lane covers cols lr*8..lr*8+8 -> slice lr>>1, half lr&1
          C4[((size_t)(lr >> 1) * NN + grow) * 2 + (lr & 1)] = v;
        }
      }
    } else {
#pragma unroll
      for (int p = 0; p < 2; ++p) {
        const int ri = p * 8 + (l >> 3);
        const int grow = bm0 + mt * 16 + ri;
        if (grow < M) {
          const uint4 v = *reinterpret_cast<const uint4*>(&st[ri * KP + (l & 7) * 8]);
          // lane covers cols (l&7)*8..+8 -> exactly slice (l&7)
          C4[(size_t)(l & 7) * NN + grow] = v;
        }
      }
    }
  }
}

// -------- gather-mean over SLICED Y1 (16-col slices), elu, bf16 h1 ----------
// slice = bid%8 (XCD affinity), 128 nodes/block, 2 lanes/node (16B uint4).
__global__ __launch_bounds__(256) void gather_sliced_16(
    const unsigned short* __restrict__ Y, const int* __restrict__ idx,
    const float* __restrict__ w, unsigned short* __restrict__ h1) {
  __shared__ int   idx_s[128][17];  // pad 17: conflict-free column reads
  __shared__ float w_s[128][17];
  const int t = threadIdx.x;
  const int slice = blockIdx.x & 7;
  const int n0 = (blockIdx.x >> 3) * 128;
#pragma unroll
  for (int j = 0; j < 8; ++j) {
    const int i = t + j * 256;         // 0..2047
    const int node = i >> 4, k = i & 15;
    int gn = n0 + node; if (gn >= NN) gn = NN - 1;   // clamp tail
    const int g = gn * (KNBR + 1) + 1 + k;
    idx_s[node][k] = __builtin_nontemporal_load(&idx[g]);
    w_s[node][k]   = __builtin_nontemporal_load(&w[g]);
  }
  __syncthreads();

  const int n = t >> 1, q = t & 1;
  const int gn = n0 + n;
  if (gn >= NN) return;
  const uint4* Y4 = reinterpret_cast<const uint4*>(Y);  // slice-row = 2 uint4
  float acc[8];
#pragma unroll
  for (int j = 0; j < 8; ++j) acc[j] = 0.f;
#pragma unroll
  for (int k = 0; k < KNBR; ++k) {
    const uint4 v  = Y4[((size_t)slice * NN + idx_s[n][k]) * 2 + q];
    const float wv = w_s[n][k];
    acc[0] += wv * bflo(v.x); acc[1] += wv * bfhi(v.x);
    acc[2] += wv * bflo(v.y); acc[3] += wv * bfhi(v.y);
    acc[4] += wv * bflo(v.z); acc[5] += wv * bfhi(v.z);
    acc[6] += wv * bflo(v.w); acc[7] += wv * bfhi(v.w);
  }
  uint4 r;
  unsigned int* rp = &r.x;
#pragma unroll
  for (int j = 0; j < 4; ++j) {
    float a = acc[2 * j] * (1.f / KNBR);
    float b = acc[2 * j + 1] * (1.f / KNBR);
    a = a > 0.f ? a : expm1f(a);  // jax.nn.elu
    b = b > 0.f ? b : expm1f(b);
    rp[j] = (unsigned int)f2bf(a) | ((unsigned int)f2bf(b) << 16);
  }
  // h1 row-major bf16: element gn*128 + slice*16 + q*8 -> uint4 index /8
  reinterpret_cast<uint4*>(h1)[(size_t)gn * 16 + slice * 2 + q] = r;
}

// -------- gather-mean over SLICED Y2 (8-col slices), fp32 out ---------------
// slice = bid%8, 256 nodes/block, 1 lane/node (16B uint4 = full slice-row).
__global__ __launch_bounds__(256) void gather_sliced_8(
    const unsigned short* __restrict__ Y, const int* __restrict__ idx,
    const float* __restrict__ w, float* __restrict__ out) {
  __shared__ int   idx_s[256][17];
  __shared__ float w_s[256][17];
  const int t = threadIdx.x;
  const int slice = blockIdx.x & 7;
  const int n0 = (blockIdx.x >> 3) * 256;
#pragma unroll
  for (int j = 0; j < 16; ++j) {
    const int i = t + j * 256;         // 0..4095
    const int node = i >> 4, k = i & 15;
    int gn = n0 + node; if (gn >= NN) gn = NN - 1;
    const int g = gn * (KNBR + 1) + 1 + k;
    idx_s[node][k] = __builtin_nontemporal_load(&idx[g]);
    w_s[node][k]   = __builtin_nontemporal_load(&w[g]);
  }
  __syncthreads();

  const int gn = n0 + t;
  if (gn >= NN) return;
  const uint4* Y4 = reinterpret_cast<const uint4*>(Y);  // slice-row = 1 uint4
  float acc[8];
#pragma unroll
  for (int j = 0; j < 8; ++j) acc[j] = 0.f;
#pragma unroll
  for (int k = 0; k < KNBR; ++k) {
    const uint4 v  = Y4[(size_t)slice * NN + idx_s[t][k]];
    const float wv = w_s[t][k];
    acc[0] += wv * bflo(v.x); acc[1] += wv * bfhi(v.x);
    acc[2] += wv * bflo(v.y); acc[3] += wv * bfhi(v.y);
    acc[4] += wv * bflo(v.z); acc[5] += wv * bfhi(v.z);
    acc[6] += wv * bflo(v.w); acc[7] += wv * bfhi(v.w);
  }
  float4 r0 = make_float4(acc[0] * (1.f / KNBR), acc[1] * (1.f / KNBR),
                          acc[2] * (1.f / KNBR), acc[3] * (1.f / KNBR));
  float4 r1 = make_float4(acc[4] * (1.f / KNBR), acc[5] * (1.f / KNBR),
                          acc[6] * (1.f / KNBR), acc[7] * (1.f / KNBR));
  float4* o4 = reinterpret_cast<float4*>(out);
  const size_t ob = ((size_t)gn * NC + slice * 8) >> 2;
  o4[ob]     = r0;
  o4[ob + 1] = r1;
}

extern "C" void kernel_launch(void* const* d_in, const int* in_sizes, int n_in,
                              void* d_out, int out_size, void* d_ws,
                              size_t ws_size, hipStream_t stream) {
  // 0:x 1:adj1_idx 2:adj1_w1(dead) 3:adj1_w2 4:adj2_idx 5:adj2_w1(dead)
  // 6:adj2_w2 7:W1 8:W2 9..18: relation params (ALL dead)
  const float* x   = (const float*)d_in[0];
  const int*   a1i = (const int*)d_in[1];
  const float* a1w = (const float*)d_in[3];
  const int*   a2i = (const int*)d_in[4];
  const float* a2w = (const float*)d_in[6];
  const float* W1  = (const float*)d_in[7];
  const float* W2  = (const float*)d_in[8];
  float*       out = (float*)d_out;

  unsigned short* Y1 = (unsigned short*)d_ws;  // sliced [8][NN][16], 12.8 MB
  unsigned short* h1 = Y1 + (size_t)NN * NF;   // row-major bf16, 12.8 MB
  unsigned short* Y2 = Y1;                     // sliced [8][NN][8], 6.4 MB

  const int gg = (NN + 127) / 128;  // 391
  gemm_mfma<NF, false><<<gg, 256, 0, stream>>>(x, W1, Y1, NN);
  gather_sliced_16<<<8 * 391, 256, 0, stream>>>(Y1, a1i, a1w, h1);  // 128 n/blk
  gemm_mfma<NC, true><<<gg, 256, 0, stream>>>(h1, W2, Y2, NN);
  gather_sliced_8<<<8 * 196, 256, 0, stream>>>(Y2, a2i, a2w, out);  // 256 n/blk
}

// Round 7
// 58.669 us; speedup vs baseline: 1.9261x; 1.9261x over previous
//
#include <hip/hip_runtime.h>
#include <hip/hip_bf16.h>

// LRGCN_Batch — reference returns ONLY h2, so the _relation() path is dead.
// Live math, REASSOCIATED ((A·x)@W == A·(x@W), A = weighted-mean gather op):
//   K1: Y1 = x @ W1                      (bf16 MFMA, fp32 acc, bf16 store)
//   K2: Y2 = elu(gather_mean(Y1)) @ W2   (FUSED: gather->LDS tile->MFMA)
//   K3: out = gather_mean(Y2)            (fp32 out)
// R7: revert R6's slicing (granule <128B destroyed coalescing: 8x L2 request
// rate, FETCH 30MB @0.9TB/s = latency-bound). Instead: fuse gather1+GEMM2
// (h1 is node-local to its block -> saves 25.6MB h1 traffic + a launch),
// gather2 granule 8B->16B, and 16-deep register load batching for MLP.
// Arithmetic identical to R5 -> absmax 2.44e-4.

#define NN   50000
#define KNBR 16
#define NF   128   // NFEAT == NHID
#define NC   64    // NCLASS

typedef short s16x8 __attribute__((ext_vector_type(8)));  // 8 bf16 (4 VGPR)
typedef float f32x4 __attribute__((ext_vector_type(4)));

static __device__ __forceinline__ unsigned short f2bf(float f) {
  __hip_bfloat16 h = __float2bfloat16(f);  // RNE
  return reinterpret_cast<unsigned short&>(h);
}
static __device__ __forceinline__ float bflo(unsigned int u) {
  return __uint_as_float(u << 16);
}
static __device__ __forceinline__ float bfhi(unsigned int u) {
  return __uint_as_float(u & 0xffff0000u);
}

// ---------------- K1: C_bf16[M x 128] = A_f32[M x 128] @ B_f32[128 x 128] --
// R5's verified MFMA GEMM (m89 fragment layouts), row-major bf16 C.
__global__ __launch_bounds__(256, 2) void gemm_mfma_128(
    const float* __restrict__ A, const float* __restrict__ B,
    unsigned short* __restrict__ C, int M) {
  constexpr int CT = 8;
  constexpr int KP = 136;       // LDS row stride in bf16 (272B: 16B-aligned)
  __shared__ unsigned short Wt_s[128 * KP];
  __shared__ unsigned short st_s[4][16 * KP];

  const int t = threadIdx.x;
  for (int i = t; i < 128 * 128; i += 256) {   // stage W^T as bf16
    const int k = i >> 7, c = i & 127;
    Wt_s[c * KP + k] = f2bf(B[i]);
  }
  __syncthreads();

  const int w   = t >> 6;
  const int l   = t & 63;
  const int lr  = l & 15;
  const int lk  = l >> 4;
  const int bm0 = blockIdx.x * 128 + w * 32;

  const int row0 = bm0 + lr, row1 = row0 + 16;
  const int r0c = row0 < M ? row0 : M - 1;
  const int r1c = row1 < M ? row1 : M - 1;

  f32x4 acc[2][CT];
#pragma unroll
  for (int mt = 0; mt < 2; ++mt)
#pragma unroll
    for (int ct = 0; ct < CT; ++ct) acc[mt][ct] = (f32x4){0.f, 0.f, 0.f, 0.f};

  const float4* A4 = reinterpret_cast<const float4*>(A);
#pragma unroll
  for (int ks = 0; ks < 4; ++ks) {
    const float4 u0 = A4[(size_t)r0c * 32 + ks * 8 + lk * 2];
    const float4 u1 = A4[(size_t)r0c * 32 + ks * 8 + lk * 2 + 1];
    const float4 v0 = A4[(size_t)r1c * 32 + ks * 8 + lk * 2];
    const float4 v1 = A4[(size_t)r1c * 32 + ks * 8 + lk * 2 + 1];
    unsigned short a0[8] = {f2bf(u0.x), f2bf(u0.y), f2bf(u0.z), f2bf(u0.w),
                            f2bf(u1.x), f2bf(u1.y), f2bf(u1.z), f2bf(u1.w)};
    unsigned short a1[8] = {f2bf(v0.x), f2bf(v0.y), f2bf(v0.z), f2bf(v0.w),
                            f2bf(v1.x), f2bf(v1.y), f2bf(v1.z), f2bf(v1.w)};
    s16x8 af0 = __builtin_bit_cast(s16x8, *(uint4*)a0);
    s16x8 af1 = __builtin_bit_cast(s16x8, *(uint4*)a1);
    const int kb = ks * 32 + lk * 8;
#pragma unroll
    for (int ct = 0; ct < CT; ++ct) {
      const uint4 bw = *reinterpret_cast<const uint4*>(&Wt_s[(ct * 16 + lr) * KP + kb]);
      const s16x8 bf = __builtin_bit_cast(s16x8, bw);
      acc[0][ct] = __builtin_amdgcn_mfma_f32_16x16x32_bf16(af0, bf, acc[0][ct], 0, 0, 0);
      acc[1][ct] = __builtin_amdgcn_mfma_f32_16x16x32_bf16(af1, bf, acc[1][ct], 0, 0, 0);
    }
  }

  unsigned short* st = st_s[w];
#pragma unroll
  for (int mt = 0; mt < 2; ++mt) {
#pragma unroll
    for (int ct = 0; ct < CT; ++ct)
#pragma unroll
      for (int r = 0; r < 4; ++r)
        st[(lk * 4 + r) * KP + ct * 16 + lr] = f2bf(acc[mt][ct][r]);
    // wave-internal LDS readback (same wave wrote it)
#pragma unroll
    for (int p = 0; p < 4; ++p) {
      const int ri = p * 4 + lk;
      const int grow = bm0 + mt * 16 + ri;
      if (grow < M) {
        const uint4 v = *reinterpret_cast<const uint4*>(&st[ri * KP + lr * 8]);
        *reinterpret_cast<uint4*>(&C[(size_t)grow * NF + lr * 8]) = v;
      }
    }
  }
}

// ---------------- K2: FUSED gather1 + elu + GEMM2 ---------------------------
// 512 threads, 64 nodes/block.
//  A: stage idx/w (1024 pairs) + W2^T bf16 [64][KP].
//  B: gather: thread=(n = half*32 + t>>4, l = t&15); v[16] batched uint4
//     loads of Y1 (16B granule, 16 lanes cover the 256B row -> coalesced);
//     weighted mean, elu, bf16 -> h1_s[n][l*8..] (stride KP).
//  C: MFMA: wave w: mt=w>>1 (16 rows), ch=w&1 (32 cols): 4 ks x 2 ct.
//  D: per-wave LDS transpose -> coalesced uint4 stores to Y2 [NN][64] bf16.
__global__ __launch_bounds__(512, 4) void gather_gemm_fused(
    const unsigned short* __restrict__ Y1, const int* __restrict__ idx,
    const float* __restrict__ w, const float* __restrict__ W2,
    unsigned short* __restrict__ Y2) {
  constexpr int KP = 136;
  __shared__ int   idx_s[64][KNBR];
  __shared__ float w_s[64][KNBR];
  __shared__ unsigned short Wt_s[64 * KP];   // W2^T: [c][k]
  __shared__ unsigned short h1_s[64 * KP];   // h1 tile: [n][f]
  __shared__ unsigned short st_s[8][16 * 40];

  const int t  = threadIdx.x;
  const int n0 = blockIdx.x * 64;

#pragma unroll
  for (int j = 0; j < 2; ++j) {              // 1024 (idx,w) pairs
    const int i = t + j * 512;
    const int node = i >> 4, k = i & 15;
    int gn = n0 + node; if (gn >= NN) gn = NN - 1;
    const int g = gn * (KNBR + 1) + 1 + k;
    idx_s[node][k] = idx[g];
    w_s[node][k]   = w[g];
  }
#pragma unroll
  for (int j = 0; j < 16; ++j) {             // W2 [128][64] -> Wt_s bf16
    const int i = t + j * 512;
    const int k = i >> 6, c = i & 63;
    Wt_s[c * KP + k] = f2bf(W2[i]);
  }
  __syncthreads();

  const uint4* Y14 = reinterpret_cast<const uint4*>(Y1);  // row = 16 uint4
  {
    const int l = t & 15;
#pragma unroll
    for (int half = 0; half < 2; ++half) {
      const int n = half * 32 + (t >> 4);
      uint4 v[KNBR];
#pragma unroll
      for (int k = 0; k < KNBR; ++k)
        v[k] = Y14[(size_t)idx_s[n][k] * 16 + l];
      float acc[8];
#pragma unroll
      for (int j = 0; j < 8; ++j) acc[j] = 0.f;
#pragma unroll
      for (int k = 0; k < KNBR; ++k) {
        const float wv = w_s[n][k];
        acc[0] += wv * bflo(v[k].x); acc[1] += wv * bfhi(v[k].x);
        acc[2] += wv * bflo(v[k].y); acc[3] += wv * bfhi(v[k].y);
        acc[4] += wv * bflo(v[k].z); acc[5] += wv * bfhi(v[k].z);
        acc[6] += wv * bflo(v[k].w); acc[7] += wv * bfhi(v[k].w);
      }
      uint4 r;
      unsigned int* rp = &r.x;
#pragma unroll
      for (int j = 0; j < 4; ++j) {
        float a = acc[2 * j] * (1.f / KNBR);
        float b = acc[2 * j + 1] * (1.f / KNBR);
        a = a > 0.f ? a : expm1f(a);  // jax.nn.elu
        b = b > 0.f ? b : expm1f(b);
        rp[j] = (unsigned int)f2bf(a) | ((unsigned int)f2bf(b) << 16);
      }
      *reinterpret_cast<uint4*>(&h1_s[n * KP + l * 8]) = r;
    }
  }
  __syncthreads();

  {  // MFMA: h1_s[64x128] @ Wt_s -> 64x64
    const int wv_ = t >> 6;        // wave 0..7
    const int l   = t & 63;
    const int lr  = l & 15;
    const int lk  = l >> 4;
    const int mt  = wv_ >> 1;      // row tile (16 rows)
    const int ch  = wv_ & 1;       // col half (32 cols)

    f32x4 acc[2];
    acc[0] = (f32x4){0.f, 0.f, 0.f, 0.f};
    acc[1] = (f32x4){0.f, 0.f, 0.f, 0.f};
#pragma unroll
    for (int ks = 0; ks < 4; ++ks) {
      const int kb = ks * 32 + lk * 8;
      const uint4 aw = *reinterpret_cast<const uint4*>(&h1_s[(mt * 16 + lr) * KP + kb]);
      const s16x8 af = __builtin_bit_cast(s16x8, aw);
#pragma unroll
      for (int ct = 0; ct < 2; ++ct) {
        const uint4 bw = *reinterpret_cast<const uint4*>(
            &Wt_s[(ch * 32 + ct * 16 + lr) * KP + kb]);
        const s16x8 bf = __builtin_bit_cast(s16x8, bw);
        acc[ct] = __builtin_amdgcn_mfma_f32_16x16x32_bf16(af, bf, acc[ct], 0, 0, 0);
      }
    }

    unsigned short* st = st_s[wv_];
#pragma unroll
    for (int ct = 0; ct < 2; ++ct)
#pragma unroll
      for (int r = 0; r < 4; ++r)
        st[(lk * 4 + r) * 40 + ct * 16 + lr] = f2bf(acc[ct][r]);
    // wave-internal readback, transposed: lane -> (row l>>2, colq l&3)
    const int ri = l >> 2;
    const int grow = n0 + mt * 16 + ri;
    if (grow < NN) {
      const uint4 v = *reinterpret_cast<const uint4*>(&st[ri * 40 + (l & 3) * 8]);
      *reinterpret_cast<uint4*>(&Y2[(size_t)grow * NC + ch * 32 + (l & 3) * 8]) = v;
    }
  }
}

// ---------------- K3: gather-mean over Y2 [NN][64] bf16 -> fp32 out ---------
// 512 threads, 64 nodes/block; thread=(n = t>>3, l = t&7): 16B granule,
// 8 lanes cover the 128B row; v[16] batched loads.
__global__ __launch_bounds__(512) void gather_mean_out(
    const unsigned short* __restrict__ Y2, const int* __restrict__ idx,
    const float* __restrict__ w, float* __restrict__ out) {
  __shared__ int   idx_s[64][KNBR];
  __shared__ float w_s[64][KNBR];
  const int t  = threadIdx.x;
  const int n0 = blockIdx.x * 64;
#pragma unroll
  for (int j = 0; j < 2; ++j) {
    const int i = t + j * 512;
    const int node = i >> 4, k = i & 15;
    int gn = n0 + node; if (gn >= NN) gn = NN - 1;
    const int g = gn * (KNBR + 1) + 1 + k;
    idx_s[node][k] = idx[g];
    w_s[node][k]   = w[g];
  }
  __syncthreads();

  const int n = t >> 3, l = t & 7;
  const int gn = n0 + n;
  if (gn >= NN) return;
  const uint4* Y24 = reinterpret_cast<const uint4*>(Y2);  // row = 8 uint4
  uint4 v[KNBR];
#pragma unroll
  for (int k = 0; k < KNBR; ++k)
    v[k] = Y24[(size_t)idx_s[n][k] * 8 + l];
  float acc[8];
#pragma unroll
  for (int j = 0; j < 8; ++j) acc[j] = 0.f;
#pragma unroll
  for (int k = 0; k < KNBR; ++k) {
    const float wv = w_s[n][k];
    acc[0] += wv * bflo(v[k].x); acc[1] += wv * bfhi(v[k].x);
    acc[2] += wv * bflo(v[k].y); acc[3] += wv * bfhi(v[k].y);
    acc[4] += wv * bflo(v[k].z); acc[5] += wv * bfhi(v[k].z);
    acc[6] += wv * bflo(v[k].w); acc[7] += wv * bfhi(v[k].w);
  }
  float4* o4 = reinterpret_cast<float4*>(out);
  const size_t ob = ((size_t)gn * NC + l * 8) >> 2;
  o4[ob] = make_float4(acc[0] * (1.f / KNBR), acc[1] * (1.f / KNBR),
                       acc[2] * (1.f / KNBR), acc[3] * (1.f / KNBR));
  o4[ob + 1] = make_float4(acc[4] * (1.f / KNBR), acc[5] * (1.f / KNBR),
                           acc[6] * (1.f / KNBR), acc[7] * (1.f / KNBR));
}

extern "C" void kernel_launch(void* const* d_in, const int* in_sizes, int n_in,
                              void* d_out, int out_size, void* d_ws,
                              size_t ws_size, hipStream_t stream) {
  // 0:x 1:adj1_idx 2:adj1_w1(dead) 3:adj1_w2 4:adj2_idx 5:adj2_w1(dead)
  // 6:adj2_w2 7:W1 8:W2 9..18: relation params (ALL dead)
  const float* x   = (const float*)d_in[0];
  const int*   a1i = (const int*)d_in[1];
  const float* a1w = (const float*)d_in[3];
  const int*   a2i = (const int*)d_in[4];
  const float* a2w = (const float*)d_in[6];
  const float* W1  = (const float*)d_in[7];
  const float* W2  = (const float*)d_in[8];
  float*       out = (float*)d_out;

  unsigned short* Y1 = (unsigned short*)d_ws;    // [NN][128] bf16, 12.8 MB
  unsigned short* Y2 = Y1 + (size_t)NN * NF;     // [NN][64]  bf16,  6.4 MB

  gemm_mfma_128<<<(NN + 127) / 128, 256, 0, stream>>>(x, W1, Y1, NN);
  gather_gemm_fused<<<(NN + 63) / 64, 512, 0, stream>>>(Y1, a1i, a1w, W2, Y2);
  gather_mean_out<<<(NN + 63) / 64, 512, 0, stream>>>(Y2, a2i, a2w, out);
}